// Round 1
// baseline (480.145 us; speedup 1.0000x reference)
//
#include <hip/hip_runtime.h>

typedef __bf16 bf16x8 __attribute__((ext_vector_type(8)));
typedef float f32x4 __attribute__((ext_vector_type(4)));
typedef unsigned short u16x4 __attribute__((ext_vector_type(4)));
typedef unsigned short u16x8 __attribute__((ext_vector_type(8)));

__device__ __forceinline__ unsigned short f2bf(float f) {
  unsigned int u = __builtin_bit_cast(unsigned int, f);
  u += 0x7FFFu + ((u >> 16) & 1u);   // round-to-nearest-even
  return (unsigned short)(u >> 16);
}

__device__ __forceinline__ bf16x8 ld_frag(const unsigned short* p) {
  return __builtin_bit_cast(bf16x8, *(const u16x8*)p);
}

#define MFMA16(a, b, c) __builtin_amdgcn_mfma_f32_16x16x32_bf16((a), (b), (c), 0, 0, 0)

// async global->LDS, 16B per lane (global_load_lds_dwordx4)
__device__ __forceinline__ void cp16(const void* g, void* l) {
  __builtin_amdgcn_global_load_lds(
      (const __attribute__((address_space(1))) unsigned int*)g,
      (__attribute__((address_space(3))) unsigned int*)l, 16, 0, 0);
}

// ---------------------------------------------------------------------------
// fp32 -> bf16 conversion (for W_triu / W_tril), float4 loads, 8B stores
// ---------------------------------------------------------------------------
__global__ __launch_bounds__(256) void cvt_bf16(const float* __restrict__ in,
                                                unsigned short* __restrict__ out,
                                                int n4) {
  int i = blockIdx.x * 256 + threadIdx.x;
  const int stride = gridDim.x * 256;
  for (; i < n4; i += stride) {
    float4 v = ((const float4*)in)[i];
    u16x4 o;
    o[0] = f2bf(v.x); o[1] = f2bf(v.y); o[2] = f2bf(v.z); o[3] = f2bf(v.w);
    ((u16x4*)out)[i] = o;
  }
}

// ---------------------------------------------------------------------------
// Per-batch: embs_kp = E * kp_W * E^T via bf16 MFMA; copy E to out0;
// scatter triu/tril (bf16) for the big GEMMs.
// One block (256 thr = 4 waves) per batch. LDS: E(8K) + W^T(8K) + T(8K).
// ---------------------------------------------------------------------------
__global__ __launch_bounds__(256) void batch_kp(
    const float* __restrict__ E,       // [B,64,64]
    const float* __restrict__ Wkp,     // [64,64]
    float* __restrict__ out0,          // [B,4096] (= copy of E)
    unsigned short* __restrict__ triu, // [B,2080] bf16
    unsigned short* __restrict__ tril) // [B,2080] bf16
{
  __shared__ __align__(16) unsigned short sE[64 * 64];
  __shared__ __align__(16) unsigned short sWt[64 * 64];  // sWt[c][d] = W[d][c]
  __shared__ __align__(16) unsigned short sT[64 * 64];

  const int b = blockIdx.x;
  const int tid = threadIdx.x;
  const float* Eb = E + (size_t)b * 4096;
  float* o0 = out0 + (size_t)b * 4096;

#pragma unroll
  for (int it = 0; it < 4; ++it) {
    const int flat = it * 1024 + tid * 4;
    float4 v = *(const float4*)(Eb + flat);
    *(float4*)(o0 + flat) = v;                 // embs_flatten output (exact fp32)
    u16x4 e;
    e[0] = f2bf(v.x); e[1] = f2bf(v.y); e[2] = f2bf(v.z); e[3] = f2bf(v.w);
    *(u16x4*)(sE + flat) = e;
    float4 wv = *(const float4*)(Wkp + flat);  // row d, cols c0..c0+3
    const int d = flat >> 6, c0 = flat & 63;
    sWt[(c0 + 0) * 64 + d] = f2bf(wv.x);
    sWt[(c0 + 1) * 64 + d] = f2bf(wv.y);
    sWt[(c0 + 2) * 64 + d] = f2bf(wv.z);
    sWt[(c0 + 3) * 64 + d] = f2bf(wv.w);
  }
  __syncthreads();

  const int lane = tid & 63, w = tid >> 6;
  const int fr = lane & 15;                 // frag row/col within 16-tile
  const int fk = (lane >> 4) << 3;          // frag k offset (0,8,16,24)
  const int qr = (lane >> 4) << 2;          // C/D quad row base

  // T = Ebf * Wkp : wave w computes rows [w*16, w*16+16)
#pragma unroll
  for (int ct = 0; ct < 4; ++ct) {
    f32x4 acc = {0.f, 0.f, 0.f, 0.f};
#pragma unroll
    for (int k2 = 0; k2 < 2; ++k2) {
      bf16x8 a = ld_frag(sE + (w * 16 + fr) * 64 + k2 * 32 + fk);
      bf16x8 bb = ld_frag(sWt + (ct * 16 + fr) * 64 + k2 * 32 + fk);
      acc = MFMA16(a, bb, acc);
    }
#pragma unroll
    for (int r = 0; r < 4; ++r)
      sT[(w * 16 + qr + r) * 64 + ct * 16 + fr] = f2bf(acc[r]);
  }
  __syncthreads();

  // K = T * E^T ; scatter into triu/tril. B-operand frag = rows of E (k-contig).
  unsigned short* tu = triu + (size_t)b * 2080;
  unsigned short* tl = tril + (size_t)b * 2080;
#pragma unroll
  for (int ct = 0; ct < 4; ++ct) {
    f32x4 acc = {0.f, 0.f, 0.f, 0.f};
#pragma unroll
    for (int k2 = 0; k2 < 2; ++k2) {
      bf16x8 a = ld_frag(sT + (w * 16 + fr) * 64 + k2 * 32 + fk);
      bf16x8 bb = ld_frag(sE + (ct * 16 + fr) * 64 + k2 * 32 + fk);
      acc = MFMA16(a, bb, acc);
    }
#pragma unroll
    for (int r = 0; r < 4; ++r) {
      const int i = w * 16 + qr + r;        // row of embs_kp
      const int j = ct * 16 + fr;           // col of embs_kp
      const unsigned short v = f2bf(acc[r]);
      if (j >= i) tu[i * 64 - ((i * (i - 1)) >> 1) + (j - i)] = v;
      if (j <= i) tl[((i * (i + 1)) >> 1) + j] = v;
    }
  }
}

// ---------------------------------------------------------------------------
// view = A[4096,2080] @ W[4096,2080]^T  (both bf16, K-contiguous "BT" GEMM)
// m97 recipe: 128x128 tile, BK=32, 4 waves x (4x4 of 16x16x32 MFMA),
// global_load_lds width=16 staging, 2-barrier K-loop. z picks view_1/view_2.
// ---------------------------------------------------------------------------
__global__ __launch_bounds__(256) void gemm_views(
    const unsigned short* __restrict__ triu, const unsigned short* __restrict__ tril,
    const unsigned short* __restrict__ Wu, const unsigned short* __restrict__ Wl,
    float* __restrict__ dout)
{
  constexpr int Kd = 2080;  // = 65 * 32, no remainder
  __shared__ __align__(16) unsigned short sA[128 * 32];
  __shared__ __align__(16) unsigned short sB[128 * 32];

  const int z = blockIdx.z;
  const unsigned short* A = z ? tril : triu;
  const unsigned short* Bw = z ? Wl : Wu;
  float* C = dout + (size_t)16777216 * (size_t)(1 + z);

  const int tid = threadIdx.x;
  const int m0 = blockIdx.y << 7, n0 = blockIdx.x << 7;

  // staging: thread t covers row t/4 (+64 on 2nd issue), k-cols (t%4)*8..+8
  const int tr = tid >> 2, tc = (tid & 3) << 3;
  const unsigned short* ga0 = A + (size_t)(m0 + tr) * Kd + tc;
  const unsigned short* ga1 = ga0 + (size_t)64 * Kd;
  const unsigned short* gb0 = Bw + (size_t)(n0 + tr) * Kd + tc;
  const unsigned short* gb1 = gb0 + (size_t)64 * Kd;
  unsigned short* la0 = sA + tid * 8;         // byte offset tid*16 (lane-contig)
  unsigned short* la1 = sA + 2048 + tid * 8;
  unsigned short* lb0 = sB + tid * 8;
  unsigned short* lb1 = sB + 2048 + tid * 8;

  const int lane = tid & 63, w = tid >> 6;
  const int wm = (w >> 1) << 6, wn = (w & 1) << 6;  // wave quadrant of 128x128
  const int fr = lane & 15, fk = (lane >> 4) << 3;

  f32x4 acc[4][4] = {};

  for (int kt = 0; kt < 65; ++kt) {
    const int ko = kt * 32;
    cp16(ga0 + ko, la0);
    cp16(ga1 + ko, la1);
    cp16(gb0 + ko, lb0);
    cp16(gb1 + ko, lb1);
    __syncthreads();   // drains vmcnt (global_load_lds) before use

    bf16x8 af[4], bfr[4];
#pragma unroll
    for (int mt = 0; mt < 4; ++mt)
      af[mt] = ld_frag(sA + (wm + mt * 16 + fr) * 32 + fk);
#pragma unroll
    for (int nt = 0; nt < 4; ++nt)
      bfr[nt] = ld_frag(sB + (wn + nt * 16 + fr) * 32 + fk);
#pragma unroll
    for (int mt = 0; mt < 4; ++mt)
#pragma unroll
      for (int nt = 0; nt < 4; ++nt)
        acc[mt][nt] = MFMA16(af[mt], bfr[nt], acc[mt][nt]);
    __syncthreads();   // protect LDS from next iteration's staging
  }

  const int qr = (lane >> 4) << 2;
#pragma unroll
  for (int mt = 0; mt < 4; ++mt) {
#pragma unroll
    for (int nt = 0; nt < 4; ++nt) {
      const int row = m0 + wm + mt * 16 + qr;
      const int col = n0 + wn + nt * 16 + fr;
      float* cp = C + (size_t)row * 4096 + col;
#pragma unroll
      for (int r = 0; r < 4; ++r)
        cp[(size_t)r * 4096] = acc[mt][nt][r];
    }
  }
}

// ---------------------------------------------------------------------------
extern "C" void kernel_launch(void* const* d_in, const int* in_sizes, int n_in,
                              void* d_out, int out_size, void* d_ws, size_t ws_size,
                              hipStream_t stream) {
  const float* feat  = (const float*)d_in[0];   // [4096,64,64]
  const float* kpW   = (const float*)d_in[1];   // [64,64]
  const float* Wtriu = (const float*)d_in[2];   // [4096,2080]
  const float* Wtril = (const float*)d_in[3];   // [4096,2080]
  float* out = (float*)d_out;                   // [emb_flat | view1 | view2]

  // workspace layout (bf16 buffers), total ~68.2 MB
  unsigned short* triu_bf = (unsigned short*)d_ws;        // 4096*2080
  unsigned short* tril_bf = triu_bf + 8519680;
  unsigned short* Wu_bf   = tril_bf + 8519680;
  unsigned short* Wl_bf   = Wu_bf + 8519680;

  cvt_bf16<<<dim3(1024), dim3(256), 0, stream>>>(Wtriu, Wu_bf, 2129920);
  cvt_bf16<<<dim3(1024), dim3(256), 0, stream>>>(Wtril, Wl_bf, 2129920);
  batch_kp<<<dim3(4096), dim3(256), 0, stream>>>(feat, kpW, out, triu_bf, tril_bf);
  gemm_views<<<dim3(32, 32, 2), dim3(256), 0, stream>>>(triu_bf, tril_bf, Wu_bf, Wl_bf, out);
}